// Round 1
// 1061.364 us; speedup vs baseline: 1.1089x; 1.1089x over previous
//
#include <hip/hip_runtime.h>
#include <cstdint>
#include <cstddef>

#define TGT  2048
#define BSZN 2
#define NH   16
#define HD   64
#define ED   1024
#define ROWS (TGT*BSZN)   // 4096
#define BHN  (BSZN*NH)    // 32

typedef __attribute__((ext_vector_type(8))) short short8;   // 8 bf16 (4 VGPRs)
typedef __attribute__((ext_vector_type(4))) float floatx4;  // MFMA C/D

__device__ inline unsigned short f2bf(float f) {            // RNE float->bf16
    unsigned u = __float_as_uint(f);
    u += 0x7FFFu + ((u >> 16) & 1u);
    return (unsigned short)(u >> 16);
}
__device__ inline float bf2f(unsigned short s) {
    return __uint_as_float(((unsigned)s) << 16);
}

// ---------------------------------------------------------------------------
// Mask prep: sniff encoding (int32 / byte / float) and expand to fp32 0/1.
// ---------------------------------------------------------------------------
__global__ __launch_bounds__(256) void prep_mask(const unsigned char* __restrict__ mraw,
                                                 float* __restrict__ maskf) {
    __shared__ int cf, cb;
    int tid = threadIdx.x;
    if (tid == 0) { cf = 0; cb = 0; }
    __syncthreads();
    int lf = 0, lb = 0;
    for (int i = tid; i < BSZN * TGT; i += 256) {
        unsigned char v = mraw[i];
        if ((i & 3) == 3 && v == 0x3F) lf++;
        if ((i & 3) != 0 && v != 0)    lb++;
    }
    if (lf) atomicAdd(&cf, lf);
    if (lb) atomicAdd(&cb, lb);
    __syncthreads();
    int fmt = (cf > 256) ? 2 : (cb > 0 ? 1 : 0);  // 2=float, 1=byte, 0=int32
    for (int i = tid; i < BSZN * TGT; i += 256) {
        bool on;
        if (fmt == 2)      on = ((const float*)mraw)[i] != 0.0f;
        else if (fmt == 1) on = (mraw[i] != 0);
        else               on = (mraw[4 * i] != 0);
        maskf[i] = on ? 1.0f : 0.0f;
    }
}

// ---------------------------------------------------------------------------
// fp32 -> (hi, lo) bf16 planes, 4 elems/thread.
// ---------------------------------------------------------------------------
__global__ __launch_bounds__(256) void convert_hilo(const float* __restrict__ src,
                                                    unsigned short* __restrict__ dh,
                                                    unsigned short* __restrict__ dl,
                                                    int n4) {
    int i = blockIdx.x * 256 + threadIdx.x;
    if (i >= n4) return;
    float4 v = ((const float4*)src)[i];
    ushort4 h, l;
    h.x = f2bf(v.x); l.x = f2bf(v.x - bf2f(h.x));
    h.y = f2bf(v.y); l.y = f2bf(v.y - bf2f(h.y));
    h.z = f2bf(v.z); l.z = f2bf(v.z - bf2f(h.z));
    h.w = f2bf(v.w); l.w = f2bf(v.w - bf2f(h.w));
    ((ushort4*)dh)[i] = h;
    ((ushort4*)dl)[i] = l;
}

// ---------------------------------------------------------------------------
// Split-bf16 NT GEMM: Y[m][n] = (sum_k A[m][k]*B[n][k] + bias[n]) * scale
// A,B given as hi/lo bf16 planes. Tile 128(M)x64(N), BK=64, 256 thr (4 waves).
// Wave w owns rows [w*32, w*32+32) via two 16-row MFMA granules.
// mode 0: fp32 -> Yf ; mode 1: bf16(hi only) -> Yb ; mode 2: vT transpose.
// MFMA 16x16x32 bf16: A[m=lane&15][k=quad*8+j]; C: col=lane&15, row=quad*4+reg.
// ---------------------------------------------------------------------------
__global__ __launch_bounds__(256) void gemm_split(
    const unsigned short* __restrict__ AH, const unsigned short* __restrict__ AL,
    const unsigned short* __restrict__ BH, const unsigned short* __restrict__ BL,
    const float* __restrict__ bias, float scale, int K,
    int mode, float* __restrict__ Yf, unsigned short* __restrict__ Yb, int ldy)
{
    // row pad to 72 (144 B, 16B-aligned, 36-bank stride -> <=2-way conflicts)
    __shared__ unsigned short Ahs[128][72];
    __shared__ unsigned short Als[128][72];
    __shared__ unsigned short Bhs[64][72];
    __shared__ unsigned short Bls[64][72];

    int tid = threadIdx.x;
    int w = tid >> 6, lane = tid & 63, lm = lane & 15, quad = lane >> 4;
    int m0 = blockIdx.y * 128, n0 = blockIdx.x * 64;

    floatx4 acc[2][4];
#pragma unroll
    for (int g = 0; g < 2; ++g)
#pragma unroll
        for (int j = 0; j < 4; ++j) acc[g][j] = (floatx4){0.f, 0.f, 0.f, 0.f};

    for (int kt = 0; kt < K; kt += 64) {
#pragma unroll
        for (int s = 0; s < 4; ++s) {            // A: 128 rows x 64 k per plane
            int idx = tid + s * 256;
            int r = idx >> 3, c8 = (idx & 7) * 8;
            *(short8*)&Ahs[r][c8] = *(const short8*)&AH[(size_t)(m0 + r) * ED + kt + c8];
            *(short8*)&Als[r][c8] = *(const short8*)&AL[(size_t)(m0 + r) * ED + kt + c8];
        }
#pragma unroll
        for (int s = 0; s < 2; ++s) {            // B: 64 rows x 64 k per plane
            int idx = tid + s * 256;
            int r = idx >> 3, c8 = (idx & 7) * 8;
            *(short8*)&Bhs[r][c8] = *(const short8*)&BH[(size_t)(n0 + r) * ED + kt + c8];
            *(short8*)&Bls[r][c8] = *(const short8*)&BL[(size_t)(n0 + r) * ED + kt + c8];
        }
        __syncthreads();
#pragma unroll
        for (int kk = 0; kk < 64; kk += 32) {
            short8 ah0 = *(const short8*)&Ahs[w * 32 + lm][kk + quad * 8];
            short8 al0 = *(const short8*)&Als[w * 32 + lm][kk + quad * 8];
            short8 ah1 = *(const short8*)&Ahs[w * 32 + 16 + lm][kk + quad * 8];
            short8 al1 = *(const short8*)&Als[w * 32 + 16 + lm][kk + quad * 8];
#pragma unroll
            for (int j = 0; j < 4; ++j) {
                short8 bh = *(const short8*)&Bhs[j * 16 + lm][kk + quad * 8];
                short8 bl = *(const short8*)&Bls[j * 16 + lm][kk + quad * 8];
                floatx4 t0 = acc[0][j];
                t0 = __builtin_amdgcn_mfma_f32_16x16x32_bf16(ah0, bl, t0, 0, 0, 0);
                t0 = __builtin_amdgcn_mfma_f32_16x16x32_bf16(al0, bh, t0, 0, 0, 0);
                t0 = __builtin_amdgcn_mfma_f32_16x16x32_bf16(ah0, bh, t0, 0, 0, 0);
                acc[0][j] = t0;
                floatx4 t1 = acc[1][j];
                t1 = __builtin_amdgcn_mfma_f32_16x16x32_bf16(ah1, bl, t1, 0, 0, 0);
                t1 = __builtin_amdgcn_mfma_f32_16x16x32_bf16(al1, bh, t1, 0, 0, 0);
                t1 = __builtin_amdgcn_mfma_f32_16x16x32_bf16(ah1, bh, t1, 0, 0, 0);
                acc[1][j] = t1;
            }
        }
        __syncthreads();
    }

    if (mode == 2) {
        // stage (val+bias) as bf16 into LDS, then write vT[bh][d][t] coalesced
        unsigned short (*Ct)[72] = Ahs;   // 128 x 64 needed; reuse A-hi plane
#pragma unroll
        for (int g = 0; g < 2; ++g)
#pragma unroll
            for (int j = 0; j < 4; ++j)
#pragma unroll
                for (int r = 0; r < 4; ++r) {
                    int row = w * 32 + g * 16 + quad * 4 + r;
                    int col = j * 16 + lm;
                    Ct[row][col] = f2bf(acc[g][j][r] + bias[n0 + col]);
                }
        __syncthreads();
        int h = n0 >> 6;
        int seg = tid >> 1, half = tid & 1;
        int bsel = seg >> 6, d = seg & 63;
        size_t base = ((size_t)((bsel * NH + h) * HD + d)) * TGT + (m0 >> 1) + half * 32;
#pragma unroll
        for (int grp = 0; grp < 4; ++grp) {
            short8 ov;
#pragma unroll
            for (int u = 0; u < 8; ++u) {
                int tl = half * 32 + grp * 8 + u;
                ov[u] = (short)Ct[tl * 2 + bsel][d];
            }
            *(short8*)&Yb[base + grp * 8] = ov;
        }
    } else {
#pragma unroll
        for (int g = 0; g < 2; ++g)
#pragma unroll
            for (int j = 0; j < 4; ++j)
#pragma unroll
                for (int r = 0; r < 4; ++r) {
                    int grow = m0 + w * 32 + g * 16 + quad * 4 + r;
                    int col = n0 + j * 16 + lm;
                    float val = (acc[g][j][r] + bias[col]) * scale;
                    if (mode == 0) Yf[(size_t)grow * ldy + col] = val;
                    else           Yb[(size_t)grow * ldy + col] = f2bf(val);
                }
    }
}

// ---------------------------------------------------------------------------
// Fused scores + mask + softmax + PV. One wg = 64 q-rows x 2048 keys, one (b,h).
// Pass 1: row sums of exp(s) (no max subtract: |s| <= ~8, masked -> 0).
// Pass 2, per 64-key chunk: recompute, normalize into LDS; write weights to
// wout (exactly once); ALSO run P·V MFMAs straight from the same LDS tile
// (A-frag m=lane&15 row = w*16+lm, k=quad*8+j — 2-way bank alias only).
// Epilogue: context written directly as hi/lo bf16 planes (skips ctx fp32).
// ---------------------------------------------------------------------------
__global__ __launch_bounds__(256) void scores_pv_fused(
    const unsigned short* __restrict__ qH, const unsigned short* __restrict__ kH,
    const unsigned short* __restrict__ vT, const float* __restrict__ maskf,
    float* __restrict__ wout,
    unsigned short* __restrict__ ctxH, unsigned short* __restrict__ ctxL)
{
    __shared__ float ot[64][68];
    int tid = threadIdx.x;
    int w = tid >> 6, lane = tid & 63, lm = lane & 15, quad = lane >> 4;
    int bh = blockIdx.y, bsel = bh >> 4, h = bh & 15;
    int t0 = blockIdx.x * 64;

    const unsigned short* qrow =
        qH + ((size_t)((t0 + w * 16 + lm) * BSZN + bsel)) * ED + h * HD + quad * 8;
    short8 a0 = *(const short8*)qrow;
    short8 a1 = *(const short8*)(qrow + 32);

    const float* mrow = maskf + bsel * TGT;
    float* wbh = wout + (size_t)bh * TGT * TGT;
    const unsigned short* vb = vT + (size_t)bh * HD * TGT;

    // ---- pass 1: row sums ----
    float rs[4] = {0.f, 0.f, 0.f, 0.f};
    for (int s0 = 0; s0 < TGT; s0 += 16) {
        int key = s0 + lm;
        const unsigned short* kr = kH + ((size_t)(key * BSZN + bsel)) * ED + h * HD + quad * 8;
        short8 b0 = *(const short8*)kr;
        short8 b1 = *(const short8*)(kr + 32);
        floatx4 s = (floatx4){0.f, 0.f, 0.f, 0.f};
        s = __builtin_amdgcn_mfma_f32_16x16x32_bf16(a0, b0, s, 0, 0, 0);
        s = __builtin_amdgcn_mfma_f32_16x16x32_bf16(a1, b1, s, 0, 0, 0);
        float mk = mrow[key];
#pragma unroll
        for (int r = 0; r < 4; ++r)
            rs[r] += (mk != 0.f) ? 0.f : __expf(s[r]);
    }
#pragma unroll
    for (int off = 1; off < 16; off <<= 1) {
#pragma unroll
        for (int r = 0; r < 4; ++r) rs[r] += __shfl_xor(rs[r], off, 64);
    }
    float rinv[4];
#pragma unroll
    for (int r = 0; r < 4; ++r) rinv[r] = 1.0f / rs[r];

    // ---- pass 2: normalize + write weights + PV accumulate ----
    floatx4 acc[4];
#pragma unroll
    for (int j = 0; j < 4; ++j) acc[j] = (floatx4){0.f, 0.f, 0.f, 0.f};

    for (int c0 = 0; c0 < TGT; c0 += 64) {
#pragma unroll
        for (int sub = 0; sub < 4; ++sub) {
            int key = c0 + sub * 16 + lm;
            const unsigned short* kr = kH + ((size_t)(key * BSZN + bsel)) * ED + h * HD + quad * 8;
            short8 b0 = *(const short8*)kr;
            short8 b1 = *(const short8*)(kr + 32);
            floatx4 s = (floatx4){0.f, 0.f, 0.f, 0.f};
            s = __builtin_amdgcn_mfma_f32_16x16x32_bf16(a0, b0, s, 0, 0, 0);
            s = __builtin_amdgcn_mfma_f32_16x16x32_bf16(a1, b1, s, 0, 0, 0);
            float mk = mrow[key];
#pragma unroll
            for (int r = 0; r < 4; ++r) {
                float e = (mk != 0.f) ? 0.f : __expf(s[r]);
                ot[w * 16 + quad * 4 + r][sub * 16 + lm] = e * rinv[r];
            }
        }
        __syncthreads();
        // weights out (fp32, written exactly once)
#pragma unroll
        for (int jj = 0; jj < 4; ++jj) {
            int idx = tid + jj * 256;
            int row = idx >> 4, c4 = (idx & 15) * 4;
            *(float4*)&wbh[(size_t)(t0 + row) * TGT + c0 + c4] = *(float4*)&ot[row][c4];
        }
        // PV: A-frag from LDS tile (rows w*16+lm), B-frag from vT (L2-resident)
#pragma unroll
        for (int kk = 0; kk < 64; kk += 32) {
            const float* pr = &ot[w * 16 + lm][kk + quad * 8];
            float4 p0 = *(const float4*)pr;
            float4 p1 = *(const float4*)(pr + 4);
            short8 af;
            af[0] = (short)f2bf(p0.x); af[1] = (short)f2bf(p0.y);
            af[2] = (short)f2bf(p0.z); af[3] = (short)f2bf(p0.w);
            af[4] = (short)f2bf(p1.x); af[5] = (short)f2bf(p1.y);
            af[6] = (short)f2bf(p1.z); af[7] = (short)f2bf(p1.w);
#pragma unroll
            for (int j = 0; j < 4; ++j) {
                short8 bf = *(const short8*)&vb[(size_t)(j * 16 + lm) * TGT + c0 + kk + quad * 8];
                acc[j] = __builtin_amdgcn_mfma_f32_16x16x32_bf16(af, bf, acc[j], 0, 0, 0);
            }
        }
        __syncthreads();
    }

    // ---- epilogue: context -> hi/lo bf16 planes directly ----
#pragma unroll
    for (int j = 0; j < 4; ++j)
#pragma unroll
        for (int r = 0; r < 4; ++r) {
            int t = t0 + w * 16 + quad * 4 + r;
            int d = j * 16 + lm;
            size_t idx = (size_t)(t * BSZN + bsel) * ED + h * HD + d;
            float val = acc[j][r];
            unsigned short hi = f2bf(val);
            ctxH[idx] = hi;
            ctxL[idx] = f2bf(val - bf2f(hi));
        }
}

// ---------------------------------------------------------------------------
extern "C" void kernel_launch(void* const* d_in, const int* in_sizes, int n_in,
                              void* d_out, int out_size, void* d_ws, size_t ws_size,
                              hipStream_t stream) {
    const float* query = (const float*)d_in[0];
    const unsigned char* mraw = (const unsigned char*)d_in[1];
    const float* qw = (const float*)d_in[2];
    const float* qb = (const float*)d_in[3];
    const float* kw = (const float*)d_in[4];
    const float* kb = (const float*)d_in[5];
    const float* vw = (const float*)d_in[6];
    const float* vb = (const float*)d_in[7];
    const float* ow = (const float*)d_in[8];
    const float* ob = (const float*)d_in[9];

    float* out  = (float*)d_out;                     // attn: ROWS*ED fp32
    float* wout = out + (size_t)ROWS * ED;           // weights: 32*2048*2048 fp32

    // ws layout (bytes), total 44.06 MB (< proven 48 MB budget):
    char* wsb = (char*)d_ws;
    float* maskf           = (float*)(wsb);                       // 16 KB
    unsigned short* qryH   = (unsigned short*)(wsb + 65536);      // 8 MB
    unsigned short* qryL   = qryH + (size_t)ROWS * ED;            // 8 MB
    unsigned short* wWH    = qryL + (size_t)ROWS * ED;            // 2 MB (rotating)
    unsigned short* wWL    = wWH + (size_t)ED * ED;               // 2 MB (rotating)
    unsigned short* qHp    = wWL + (size_t)ED * ED;               // 8 MB
    unsigned short* kHp    = qHp + (size_t)ROWS * ED;             // 8 MB
    unsigned short* vT     = kHp + (size_t)ROWS * ED;             // 8 MB
    // ctx hi/lo planes alias qryH/qryL (dead after the 3 projection GEMMs).
    // NOTE: must NOT alias qHp/kHp — scores_pv_fused reads those while writing ctx.
    unsigned short* ctxH   = qryH;
    unsigned short* ctxL   = qryL;

    dim3 blk(256);
    dim3 ggrid(ED / 64, ROWS / 128);   // (16, 32)

    prep_mask<<<1, blk, 0, stream>>>(mraw, maskf);
    convert_hilo<<<(ROWS * ED / 4 + 255) / 256, blk, 0, stream>>>(query, qryH, qryL, ROWS * ED / 4);

    // Q projection -> bf16 plane, scale 0.125 (bias before scale)
    convert_hilo<<<(ED * ED / 4 + 255) / 256, blk, 0, stream>>>(qw, wWH, wWL, ED * ED / 4);
    gemm_split<<<ggrid, blk, 0, stream>>>(qryH, qryL, wWH, wWL, qb, 0.125f, ED, 1, nullptr, qHp, ED);
    // K projection -> bf16 plane
    convert_hilo<<<(ED * ED / 4 + 255) / 256, blk, 0, stream>>>(kw, wWH, wWL, ED * ED / 4);
    gemm_split<<<ggrid, blk, 0, stream>>>(qryH, qryL, wWH, wWL, kb, 1.0f, ED, 1, nullptr, kHp, ED);
    // V projection -> vT bf16 [bh][d][t]
    convert_hilo<<<(ED * ED / 4 + 255) / 256, blk, 0, stream>>>(vw, wWH, wWL, ED * ED / 4);
    gemm_split<<<ggrid, blk, 0, stream>>>(qryH, qryL, wWH, wWL, vb, 1.0f, ED, 2, nullptr, vT, ED);

    // fused scores + mask + softmax + PV:
    //   weights -> wout (written exactly once), context -> ctxH/ctxL bf16 planes
    scores_pv_fused<<<dim3(TGT / 64, BHN), blk, 0, stream>>>(qHp, kHp, vT, maskf, wout, ctxH, ctxL);

    // out projection: ctx planes -> fp32 out
    convert_hilo<<<(ED * ED / 4 + 255) / 256, blk, 0, stream>>>(ow, wWH, wWL, ED * ED / 4);
    gemm_split<<<ggrid, blk, 0, stream>>>(ctxH, ctxL, wWH, wWL, ob, 1.0f, ED, 0, out, nullptr, ED);
}

// Round 2
// 1036.466 us; speedup vs baseline: 1.1355x; 1.0240x over previous
//
#include <hip/hip_runtime.h>
#include <cstdint>
#include <cstddef>

#define TGT  2048
#define BSZN 2
#define NH   16
#define HD   64
#define ED   1024
#define ROWS (TGT*BSZN)   // 4096
#define BHN  (BSZN*NH)    // 32

typedef __attribute__((ext_vector_type(8))) short short8;   // 8 bf16 (4 VGPRs)
typedef __attribute__((ext_vector_type(4))) float floatx4;  // MFMA C/D

__device__ inline unsigned short f2bf(float f) {            // RNE float->bf16
    unsigned u = __float_as_uint(f);
    u += 0x7FFFu + ((u >> 16) & 1u);
    return (unsigned short)(u >> 16);
}
__device__ inline float bf2f(unsigned short s) {
    return __uint_as_float(((unsigned)s) << 16);
}

// ---------------------------------------------------------------------------
// Mask prep: sniff encoding (int32 / byte / float) and expand to fp32 0/1.
// ---------------------------------------------------------------------------
__global__ __launch_bounds__(256) void prep_mask(const unsigned char* __restrict__ mraw,
                                                 float* __restrict__ maskf) {
    __shared__ int cf, cb;
    int tid = threadIdx.x;
    if (tid == 0) { cf = 0; cb = 0; }
    __syncthreads();
    int lf = 0, lb = 0;
    for (int i = tid; i < BSZN * TGT; i += 256) {
        unsigned char v = mraw[i];
        if ((i & 3) == 3 && v == 0x3F) lf++;
        if ((i & 3) != 0 && v != 0)    lb++;
    }
    if (lf) atomicAdd(&cf, lf);
    if (lb) atomicAdd(&cb, lb);
    __syncthreads();
    int fmt = (cf > 256) ? 2 : (cb > 0 ? 1 : 0);  // 2=float, 1=byte, 0=int32
    for (int i = tid; i < BSZN * TGT; i += 256) {
        bool on;
        if (fmt == 2)      on = ((const float*)mraw)[i] != 0.0f;
        else if (fmt == 1) on = (mraw[i] != 0);
        else               on = (mraw[4 * i] != 0);
        maskf[i] = on ? 1.0f : 0.0f;
    }
}

// ---------------------------------------------------------------------------
// fp32 -> (hi, lo) bf16 planes, 4 elems/thread.
// ---------------------------------------------------------------------------
__global__ __launch_bounds__(256) void convert_hilo(const float* __restrict__ src,
                                                    unsigned short* __restrict__ dh,
                                                    unsigned short* __restrict__ dl,
                                                    int n4) {
    int i = blockIdx.x * 256 + threadIdx.x;
    if (i >= n4) return;
    float4 v = ((const float4*)src)[i];
    ushort4 h, l;
    h.x = f2bf(v.x); l.x = f2bf(v.x - bf2f(h.x));
    h.y = f2bf(v.y); l.y = f2bf(v.y - bf2f(h.y));
    h.z = f2bf(v.z); l.z = f2bf(v.z - bf2f(h.z));
    h.w = f2bf(v.w); l.w = f2bf(v.w - bf2f(h.w));
    ((ushort4*)dh)[i] = h;
    ((ushort4*)dl)[i] = l;
}

// ---------------------------------------------------------------------------
// Split-bf16 NT GEMM: Y[m][n] = (sum_k A[m][k]*B[n][k] + bias[n]) * scale
// A,B given as hi/lo bf16 planes. Tile 128(M)x64(N), BK=64, 256 thr (4 waves).
// Wave w owns rows [w*32, w*32+32) via two 16-row MFMA granules.
// mode 0: fp32 -> Yf ; mode 1: bf16(hi only) -> Yb ; mode 2: vT transpose.
// MFMA 16x16x32 bf16: A[m=lane&15][k=quad*8+j]; C: col=lane&15, row=quad*4+reg.
// ---------------------------------------------------------------------------
__global__ __launch_bounds__(256) void gemm_split(
    const unsigned short* __restrict__ AH, const unsigned short* __restrict__ AL,
    const unsigned short* __restrict__ BH, const unsigned short* __restrict__ BL,
    const float* __restrict__ bias, float scale, int K,
    int mode, float* __restrict__ Yf, unsigned short* __restrict__ Yb, int ldy)
{
    // row pad to 72 (144 B, 16B-aligned, 36-bank stride -> <=2-way conflicts)
    __shared__ unsigned short Ahs[128][72];
    __shared__ unsigned short Als[128][72];
    __shared__ unsigned short Bhs[64][72];
    __shared__ unsigned short Bls[64][72];

    int tid = threadIdx.x;
    int w = tid >> 6, lane = tid & 63, lm = lane & 15, quad = lane >> 4;
    int m0 = blockIdx.y * 128, n0 = blockIdx.x * 64;

    floatx4 acc[2][4];
#pragma unroll
    for (int g = 0; g < 2; ++g)
#pragma unroll
        for (int j = 0; j < 4; ++j) acc[g][j] = (floatx4){0.f, 0.f, 0.f, 0.f};

    for (int kt = 0; kt < K; kt += 64) {
#pragma unroll
        for (int s = 0; s < 4; ++s) {            // A: 128 rows x 64 k per plane
            int idx = tid + s * 256;
            int r = idx >> 3, c8 = (idx & 7) * 8;
            *(short8*)&Ahs[r][c8] = *(const short8*)&AH[(size_t)(m0 + r) * ED + kt + c8];
            *(short8*)&Als[r][c8] = *(const short8*)&AL[(size_t)(m0 + r) * ED + kt + c8];
        }
#pragma unroll
        for (int s = 0; s < 2; ++s) {            // B: 64 rows x 64 k per plane
            int idx = tid + s * 256;
            int r = idx >> 3, c8 = (idx & 7) * 8;
            *(short8*)&Bhs[r][c8] = *(const short8*)&BH[(size_t)(n0 + r) * ED + kt + c8];
            *(short8*)&Bls[r][c8] = *(const short8*)&BL[(size_t)(n0 + r) * ED + kt + c8];
        }
        __syncthreads();
#pragma unroll
        for (int kk = 0; kk < 64; kk += 32) {
            short8 ah0 = *(const short8*)&Ahs[w * 32 + lm][kk + quad * 8];
            short8 al0 = *(const short8*)&Als[w * 32 + lm][kk + quad * 8];
            short8 ah1 = *(const short8*)&Ahs[w * 32 + 16 + lm][kk + quad * 8];
            short8 al1 = *(const short8*)&Als[w * 32 + 16 + lm][kk + quad * 8];
#pragma unroll
            for (int j = 0; j < 4; ++j) {
                short8 bh = *(const short8*)&Bhs[j * 16 + lm][kk + quad * 8];
                short8 bl = *(const short8*)&Bls[j * 16 + lm][kk + quad * 8];
                floatx4 t0 = acc[0][j];
                t0 = __builtin_amdgcn_mfma_f32_16x16x32_bf16(ah0, bl, t0, 0, 0, 0);
                t0 = __builtin_amdgcn_mfma_f32_16x16x32_bf16(al0, bh, t0, 0, 0, 0);
                t0 = __builtin_amdgcn_mfma_f32_16x16x32_bf16(ah0, bh, t0, 0, 0, 0);
                acc[0][j] = t0;
                floatx4 t1 = acc[1][j];
                t1 = __builtin_amdgcn_mfma_f32_16x16x32_bf16(ah1, bl, t1, 0, 0, 0);
                t1 = __builtin_amdgcn_mfma_f32_16x16x32_bf16(al1, bh, t1, 0, 0, 0);
                t1 = __builtin_amdgcn_mfma_f32_16x16x32_bf16(ah1, bh, t1, 0, 0, 0);
                acc[1][j] = t1;
            }
        }
        __syncthreads();
    }

    if (mode == 2) {
        // stage (val+bias) as bf16 into LDS, then write vT[bh][d][t] coalesced
        unsigned short (*Ct)[72] = Ahs;   // 128 x 64 needed; reuse A-hi plane
#pragma unroll
        for (int g = 0; g < 2; ++g)
#pragma unroll
            for (int j = 0; j < 4; ++j)
#pragma unroll
                for (int r = 0; r < 4; ++r) {
                    int row = w * 32 + g * 16 + quad * 4 + r;
                    int col = j * 16 + lm;
                    Ct[row][col] = f2bf(acc[g][j][r] + bias[n0 + col]);
                }
        __syncthreads();
        int h = n0 >> 6;
        int seg = tid >> 1, half = tid & 1;
        int bsel = seg >> 6, d = seg & 63;
        size_t base = ((size_t)((bsel * NH + h) * HD + d)) * TGT + (m0 >> 1) + half * 32;
#pragma unroll
        for (int grp = 0; grp < 4; ++grp) {
            short8 ov;
#pragma unroll
            for (int u = 0; u < 8; ++u) {
                int tl = half * 32 + grp * 8 + u;
                ov[u] = (short)Ct[tl * 2 + bsel][d];
            }
            *(short8*)&Yb[base + grp * 8] = ov;
        }
    } else {
#pragma unroll
        for (int g = 0; g < 2; ++g)
#pragma unroll
            for (int j = 0; j < 4; ++j)
#pragma unroll
                for (int r = 0; r < 4; ++r) {
                    int grow = m0 + w * 32 + g * 16 + quad * 4 + r;
                    int col = n0 + j * 16 + lm;
                    float val = (acc[g][j][r] + bias[col]) * scale;
                    if (mode == 0) Yf[(size_t)grow * ldy + col] = val;
                    else           Yb[(size_t)grow * ldy + col] = f2bf(val);
                }
    }
}

// ---------------------------------------------------------------------------
// Fused scores + mask + softmax + PV, barrier-free pass 2.
// One wg = 64 q-rows x 2048 keys for one (b,h); each wave owns 16 rows
// INDEPENDENTLY (private LDS P-scratch, no __syncthreads in the main loops).
// Pass 1: row sums of exp(s) (no max subtract: |s| <= ~8, masked -> 0),
//         unrolled x2 for load-level parallelism.
// Pass 2, per 64-key chunk: QK -> regs; weights stored DIRECTLY from regs
// (nontemporal, coalesced 64B per quad); fp32 P also dropped into the wave's
// private LDS tile, re-read as PV A-fragments (same-wave LDS => no barrier).
// Block remap: each XCD gets 4 consecutive bh slices (K+V+Q ~3MB < 4MB L2).
// Epilogue: context written directly as hi/lo bf16 planes.
// ---------------------------------------------------------------------------
__global__ __launch_bounds__(256) void scores_pv_fused(
    const unsigned short* __restrict__ qH, const unsigned short* __restrict__ kH,
    const unsigned short* __restrict__ vT, const float* __restrict__ maskf,
    float* __restrict__ wout,
    unsigned short* __restrict__ ctxH, unsigned short* __restrict__ ctxL)
{
    __shared__ float ot[4][16][68];     // per-wave private P scratch
    int tid = threadIdx.x;
    int w = tid >> 6, lane = tid & 63, lm = lane & 15, quad = lane >> 4;

    // XCD-aware remap: slot -> (bh, t-chunk); 1024 wgs, 8 XCDs, bijective.
    int slot = blockIdx.y * gridDim.x + blockIdx.x;
    int xcd = slot & 7, rr = slot >> 3;
    int bh = xcd * 4 + (rr >> 5);
    int t0 = (rr & 31) * 64;
    int bsel = bh >> 4, h = bh & 15;

    const unsigned short* qrow =
        qH + ((size_t)((t0 + w * 16 + lm) * BSZN + bsel)) * ED + h * HD + quad * 8;
    short8 a0 = *(const short8*)qrow;
    short8 a1 = *(const short8*)(qrow + 32);

    const float* mrow = maskf + bsel * TGT;
    float* wbh = wout + (size_t)bh * TGT * TGT;
    const unsigned short* vb = vT + (size_t)bh * HD * TGT;

    // ---- pass 1: row sums (x2 unroll, independent score accumulators) ----
    float rs[4] = {0.f, 0.f, 0.f, 0.f};
    for (int s0 = 0; s0 < TGT; s0 += 32) {
        int keyA = s0 + lm, keyB = s0 + 16 + lm;
        const unsigned short* krA = kH + ((size_t)(keyA * BSZN + bsel)) * ED + h * HD + quad * 8;
        const unsigned short* krB = kH + ((size_t)(keyB * BSZN + bsel)) * ED + h * HD + quad * 8;
        short8 b0A = *(const short8*)krA;
        short8 b1A = *(const short8*)(krA + 32);
        short8 b0B = *(const short8*)krB;
        short8 b1B = *(const short8*)(krB + 32);
        float mkA = mrow[keyA], mkB = mrow[keyB];
        floatx4 sA = (floatx4){0.f, 0.f, 0.f, 0.f};
        floatx4 sB = (floatx4){0.f, 0.f, 0.f, 0.f};
        sA = __builtin_amdgcn_mfma_f32_16x16x32_bf16(a0, b0A, sA, 0, 0, 0);
        sB = __builtin_amdgcn_mfma_f32_16x16x32_bf16(a0, b0B, sB, 0, 0, 0);
        sA = __builtin_amdgcn_mfma_f32_16x16x32_bf16(a1, b1A, sA, 0, 0, 0);
        sB = __builtin_amdgcn_mfma_f32_16x16x32_bf16(a1, b1B, sB, 0, 0, 0);
#pragma unroll
        for (int r = 0; r < 4; ++r) {
            rs[r] += (mkA != 0.f) ? 0.f : __expf(sA[r]);   // same add order as
            rs[r] += (mkB != 0.f) ? 0.f : __expf(sB[r]);   // before: s0, s0+16
        }
    }
#pragma unroll
    for (int off = 1; off < 16; off <<= 1) {
#pragma unroll
        for (int r = 0; r < 4; ++r) rs[r] += __shfl_xor(rs[r], off, 64);
    }
    float rinv[4];
#pragma unroll
    for (int r = 0; r < 4; ++r) rinv[r] = 1.0f / rs[r];

    // ---- pass 2: weights from regs (nt) + PV from private LDS, no barriers ----
    floatx4 acc[4];
#pragma unroll
    for (int j = 0; j < 4; ++j) acc[j] = (floatx4){0.f, 0.f, 0.f, 0.f};

    float* wrow = wbh + (size_t)(t0 + w * 16 + quad * 4) * TGT;  // rows quad*4+r

    for (int c0 = 0; c0 < TGT; c0 += 64) {
#pragma unroll
        for (int sub = 0; sub < 4; ++sub) {
            int key = c0 + sub * 16 + lm;
            const unsigned short* kr = kH + ((size_t)(key * BSZN + bsel)) * ED + h * HD + quad * 8;
            short8 b0 = *(const short8*)kr;
            short8 b1 = *(const short8*)(kr + 32);
            floatx4 s = (floatx4){0.f, 0.f, 0.f, 0.f};
            s = __builtin_amdgcn_mfma_f32_16x16x32_bf16(a0, b0, s, 0, 0, 0);
            s = __builtin_amdgcn_mfma_f32_16x16x32_bf16(a1, b1, s, 0, 0, 0);
            float mk = mrow[key];
#pragma unroll
            for (int r = 0; r < 4; ++r) {
                float e = (mk != 0.f) ? 0.f : __expf(s[r]);
                float v = e * rinv[r];
                __builtin_nontemporal_store(v, &wrow[(size_t)r * TGT + key]);
                ot[w][quad * 4 + r][sub * 16 + lm] = v;   // 2-way bank alias: free
            }
        }
        // PV: A-frag from this wave's own 16 rows (same-wave LDS, no barrier)
#pragma unroll
        for (int kk = 0; kk < 64; kk += 32) {
            const float* pr = &ot[w][lm][kk + quad * 8];
            float4 p0 = *(const float4*)pr;
            float4 p1 = *(const float4*)(pr + 4);
            short8 af;
            af[0] = (short)f2bf(p0.x); af[1] = (short)f2bf(p0.y);
            af[2] = (short)f2bf(p0.z); af[3] = (short)f2bf(p0.w);
            af[4] = (short)f2bf(p1.x); af[5] = (short)f2bf(p1.y);
            af[6] = (short)f2bf(p1.z); af[7] = (short)f2bf(p1.w);
#pragma unroll
            for (int j = 0; j < 4; ++j) {
                short8 bf = *(const short8*)&vb[(size_t)(j * 16 + lm) * TGT + c0 + kk + quad * 8];
                acc[j] = __builtin_amdgcn_mfma_f32_16x16x32_bf16(af, bf, acc[j], 0, 0, 0);
            }
        }
    }

    // ---- epilogue: context -> hi/lo bf16 planes directly ----
#pragma unroll
    for (int j = 0; j < 4; ++j)
#pragma unroll
        for (int r = 0; r < 4; ++r) {
            int t = t0 + w * 16 + quad * 4 + r;
            int d = j * 16 + lm;
            size_t idx = (size_t)(t * BSZN + bsel) * ED + h * HD + d;
            float val = acc[j][r];
            unsigned short hi = f2bf(val);
            ctxH[idx] = hi;
            ctxL[idx] = f2bf(val - bf2f(hi));
        }
}

// ---------------------------------------------------------------------------
extern "C" void kernel_launch(void* const* d_in, const int* in_sizes, int n_in,
                              void* d_out, int out_size, void* d_ws, size_t ws_size,
                              hipStream_t stream) {
    const float* query = (const float*)d_in[0];
    const unsigned char* mraw = (const unsigned char*)d_in[1];
    const float* qw = (const float*)d_in[2];
    const float* qb = (const float*)d_in[3];
    const float* kw = (const float*)d_in[4];
    const float* kb = (const float*)d_in[5];
    const float* vw = (const float*)d_in[6];
    const float* vb = (const float*)d_in[7];
    const float* ow = (const float*)d_in[8];
    const float* ob = (const float*)d_in[9];

    float* out  = (float*)d_out;                     // attn: ROWS*ED fp32
    float* wout = out + (size_t)ROWS * ED;           // weights: 32*2048*2048 fp32

    // ws layout (bytes), total 44.06 MB (< proven 48 MB budget):
    char* wsb = (char*)d_ws;
    float* maskf           = (float*)(wsb);                       // 16 KB
    unsigned short* qryH   = (unsigned short*)(wsb + 65536);      // 8 MB
    unsigned short* qryL   = qryH + (size_t)ROWS * ED;            // 8 MB
    unsigned short* wWH    = qryL + (size_t)ROWS * ED;            // 2 MB (rotating)
    unsigned short* wWL    = wWH + (size_t)ED * ED;               // 2 MB (rotating)
    unsigned short* qHp    = wWL + (size_t)ED * ED;               // 8 MB
    unsigned short* kHp    = qHp + (size_t)ROWS * ED;             // 8 MB
    unsigned short* vT     = kHp + (size_t)ROWS * ED;             // 8 MB
    // ctx hi/lo planes alias qryH/qryL (dead after the 3 projection GEMMs).
    // NOTE: must NOT alias qHp/kHp — scores_pv_fused reads those while writing ctx.
    unsigned short* ctxH   = qryH;
    unsigned short* ctxL   = qryL;

    dim3 blk(256);
    dim3 ggrid(ED / 64, ROWS / 128);   // (16, 32)

    prep_mask<<<1, blk, 0, stream>>>(mraw, maskf);
    convert_hilo<<<(ROWS * ED / 4 + 255) / 256, blk, 0, stream>>>(query, qryH, qryL, ROWS * ED / 4);

    // Q projection -> bf16 plane, scale 0.125 (bias before scale)
    convert_hilo<<<(ED * ED / 4 + 255) / 256, blk, 0, stream>>>(qw, wWH, wWL, ED * ED / 4);
    gemm_split<<<ggrid, blk, 0, stream>>>(qryH, qryL, wWH, wWL, qb, 0.125f, ED, 1, nullptr, qHp, ED);
    // K projection -> bf16 plane
    convert_hilo<<<(ED * ED / 4 + 255) / 256, blk, 0, stream>>>(kw, wWH, wWL, ED * ED / 4);
    gemm_split<<<ggrid, blk, 0, stream>>>(qryH, qryL, wWH, wWL, kb, 1.0f, ED, 1, nullptr, kHp, ED);
    // V projection -> vT bf16 [bh][d][t]
    convert_hilo<<<(ED * ED / 4 + 255) / 256, blk, 0, stream>>>(vw, wWH, wWL, ED * ED / 4);
    gemm_split<<<ggrid, blk, 0, stream>>>(qryH, qryL, wWH, wWL, vb, 1.0f, ED, 2, nullptr, vT, ED);

    // fused scores + mask + softmax + PV:
    //   weights -> wout (written exactly once), context -> ctxH/ctxL bf16 planes
    scores_pv_fused<<<dim3(TGT / 64, BHN), blk, 0, stream>>>(qHp, kHp, vT, maskf, wout, ctxH, ctxL);

    // out projection: ctx planes -> fp32 out
    convert_hilo<<<(ED * ED / 4 + 255) / 256, blk, 0, stream>>>(ow, wWH, wWL, ED * ED / 4);
    gemm_split<<<ggrid, blk, 0, stream>>>(ctxH, ctxL, wWH, wWL, ob, 1.0f, ED, 0, out, nullptr, ED);
}

// Round 4
// 1008.544 us; speedup vs baseline: 1.1670x; 1.0277x over previous
//
#include <hip/hip_runtime.h>
#include <cstdint>
#include <cstddef>

#define TGT  2048
#define BSZN 2
#define NH   16
#define HD   64
#define ED   1024
#define ROWS (TGT*BSZN)   // 4096
#define BHN  (BSZN*NH)    // 32

typedef __attribute__((ext_vector_type(8))) short short8;   // 8 bf16 (4 VGPRs)
typedef __attribute__((ext_vector_type(4))) float floatx4;  // MFMA C/D

__device__ inline unsigned short f2bf(float f) {            // RNE float->bf16
    unsigned u = __float_as_uint(f);
    u += 0x7FFFu + ((u >> 16) & 1u);
    return (unsigned short)(u >> 16);
}
__device__ inline float bf2f(unsigned short s) {
    return __uint_as_float(((unsigned)s) << 16);
}

// ---------------------------------------------------------------------------
// Mask prep: sniff encoding (int32 / byte / float) and expand to fp32 0/1.
// ---------------------------------------------------------------------------
__global__ __launch_bounds__(256) void prep_mask(const unsigned char* __restrict__ mraw,
                                                 float* __restrict__ maskf) {
    __shared__ int cf, cb;
    int tid = threadIdx.x;
    if (tid == 0) { cf = 0; cb = 0; }
    __syncthreads();
    int lf = 0, lb = 0;
    for (int i = tid; i < BSZN * TGT; i += 256) {
        unsigned char v = mraw[i];
        if ((i & 3) == 3 && v == 0x3F) lf++;
        if ((i & 3) != 0 && v != 0)    lb++;
    }
    if (lf) atomicAdd(&cf, lf);
    if (lb) atomicAdd(&cb, lb);
    __syncthreads();
    int fmt = (cf > 256) ? 2 : (cb > 0 ? 1 : 0);  // 2=float, 1=byte, 0=int32
    for (int i = tid; i < BSZN * TGT; i += 256) {
        bool on;
        if (fmt == 2)      on = ((const float*)mraw)[i] != 0.0f;
        else if (fmt == 1) on = (mraw[i] != 0);
        else               on = (mraw[4 * i] != 0);
        maskf[i] = on ? 1.0f : 0.0f;
    }
}

// ---------------------------------------------------------------------------
// fp32 -> (hi, lo) bf16 planes, 4 elems/thread.
// ---------------------------------------------------------------------------
__global__ __launch_bounds__(256) void convert_hilo(const float* __restrict__ src,
                                                    unsigned short* __restrict__ dh,
                                                    unsigned short* __restrict__ dl,
                                                    int n4) {
    int i = blockIdx.x * 256 + threadIdx.x;
    if (i >= n4) return;
    float4 v = ((const float4*)src)[i];
    ushort4 h, l;
    h.x = f2bf(v.x); l.x = f2bf(v.x - bf2f(h.x));
    h.y = f2bf(v.y); l.y = f2bf(v.y - bf2f(h.y));
    h.z = f2bf(v.z); l.z = f2bf(v.z - bf2f(h.z));
    h.w = f2bf(v.w); l.w = f2bf(v.w - bf2f(h.w));
    ((ushort4*)dh)[i] = h;
    ((ushort4*)dl)[i] = l;
}

// ---------------------------------------------------------------------------
// Split-bf16 NT GEMM: Y[m][n] = (sum_k A[m][k]*B[n][k] + bias[n]) * scale
// A,B given as hi/lo bf16 planes. Tile 128(M)x64(N), BK=64, 256 thr (4 waves).
// Wave w owns rows [w*32, w*32+32) via two 16-row MFMA granules.
// mode 0: fp32 -> Yf ; mode 1: bf16(hi only) -> Yb ; mode 2: vT transpose.
// MFMA 16x16x32 bf16: A[m=lane&15][k=quad*8+j]; C: col=lane&15, row=quad*4+reg.
// ---------------------------------------------------------------------------
__global__ __launch_bounds__(256) void gemm_split(
    const unsigned short* __restrict__ AH, const unsigned short* __restrict__ AL,
    const unsigned short* __restrict__ BH, const unsigned short* __restrict__ BL,
    const float* __restrict__ bias, float scale, int K,
    int mode, float* __restrict__ Yf, unsigned short* __restrict__ Yb, int ldy)
{
    // row pad to 72 (144 B, 16B-aligned, 36-bank stride -> <=2-way conflicts)
    __shared__ unsigned short Ahs[128][72];
    __shared__ unsigned short Als[128][72];
    __shared__ unsigned short Bhs[64][72];
    __shared__ unsigned short Bls[64][72];

    int tid = threadIdx.x;
    int w = tid >> 6, lane = tid & 63, lm = lane & 15, quad = lane >> 4;
    int m0 = blockIdx.y * 128, n0 = blockIdx.x * 64;

    floatx4 acc[2][4];
#pragma unroll
    for (int g = 0; g < 2; ++g)
#pragma unroll
        for (int j = 0; j < 4; ++j) acc[g][j] = (floatx4){0.f, 0.f, 0.f, 0.f};

    for (int kt = 0; kt < K; kt += 64) {
#pragma unroll
        for (int s = 0; s < 4; ++s) {            // A: 128 rows x 64 k per plane
            int idx = tid + s * 256;
            int r = idx >> 3, c8 = (idx & 7) * 8;
            *(short8*)&Ahs[r][c8] = *(const short8*)&AH[(size_t)(m0 + r) * ED + kt + c8];
            *(short8*)&Als[r][c8] = *(const short8*)&AL[(size_t)(m0 + r) * ED + kt + c8];
        }
#pragma unroll
        for (int s = 0; s < 2; ++s) {            // B: 64 rows x 64 k per plane
            int idx = tid + s * 256;
            int r = idx >> 3, c8 = (idx & 7) * 8;
            *(short8*)&Bhs[r][c8] = *(const short8*)&BH[(size_t)(n0 + r) * ED + kt + c8];
            *(short8*)&Bls[r][c8] = *(const short8*)&BL[(size_t)(n0 + r) * ED + kt + c8];
        }
        __syncthreads();
#pragma unroll
        for (int kk = 0; kk < 64; kk += 32) {
            short8 ah0 = *(const short8*)&Ahs[w * 32 + lm][kk + quad * 8];
            short8 al0 = *(const short8*)&Als[w * 32 + lm][kk + quad * 8];
            short8 ah1 = *(const short8*)&Ahs[w * 32 + 16 + lm][kk + quad * 8];
            short8 al1 = *(const short8*)&Als[w * 32 + 16 + lm][kk + quad * 8];
#pragma unroll
            for (int j = 0; j < 4; ++j) {
                short8 bh = *(const short8*)&Bhs[j * 16 + lm][kk + quad * 8];
                short8 bl = *(const short8*)&Bls[j * 16 + lm][kk + quad * 8];
                floatx4 t0 = acc[0][j];
                t0 = __builtin_amdgcn_mfma_f32_16x16x32_bf16(ah0, bl, t0, 0, 0, 0);
                t0 = __builtin_amdgcn_mfma_f32_16x16x32_bf16(al0, bh, t0, 0, 0, 0);
                t0 = __builtin_amdgcn_mfma_f32_16x16x32_bf16(ah0, bh, t0, 0, 0, 0);
                acc[0][j] = t0;
                floatx4 t1 = acc[1][j];
                t1 = __builtin_amdgcn_mfma_f32_16x16x32_bf16(ah1, bl, t1, 0, 0, 0);
                t1 = __builtin_amdgcn_mfma_f32_16x16x32_bf16(al1, bh, t1, 0, 0, 0);
                t1 = __builtin_amdgcn_mfma_f32_16x16x32_bf16(ah1, bh, t1, 0, 0, 0);
                acc[1][j] = t1;
            }
        }
        __syncthreads();
    }

    if (mode == 2) {
        // stage (val+bias) as bf16 into LDS, then write vT[bh][d][t] coalesced
        unsigned short (*Ct)[72] = Ahs;   // 128 x 64 needed; reuse A-hi plane
#pragma unroll
        for (int g = 0; g < 2; ++g)
#pragma unroll
            for (int j = 0; j < 4; ++j)
#pragma unroll
                for (int r = 0; r < 4; ++r) {
                    int row = w * 32 + g * 16 + quad * 4 + r;
                    int col = j * 16 + lm;
                    Ct[row][col] = f2bf(acc[g][j][r] + bias[n0 + col]);
                }
        __syncthreads();
        int h = n0 >> 6;
        int seg = tid >> 1, half = tid & 1;
        int bsel = seg >> 6, d = seg & 63;
        size_t base = ((size_t)((bsel * NH + h) * HD + d)) * TGT + (m0 >> 1) + half * 32;
#pragma unroll
        for (int grp = 0; grp < 4; ++grp) {
            short8 ov;
#pragma unroll
            for (int u = 0; u < 8; ++u) {
                int tl = half * 32 + grp * 8 + u;
                ov[u] = (short)Ct[tl * 2 + bsel][d];
            }
            *(short8*)&Yb[base + grp * 8] = ov;
        }
    } else {
#pragma unroll
        for (int g = 0; g < 2; ++g)
#pragma unroll
            for (int j = 0; j < 4; ++j)
#pragma unroll
                for (int r = 0; r < 4; ++r) {
                    int grow = m0 + w * 32 + g * 16 + quad * 4 + r;
                    int col = n0 + j * 16 + lm;
                    float val = (acc[g][j][r] + bias[col]) * scale;
                    if (mode == 0) Yf[(size_t)grow * ldy + col] = val;
                    else           Yb[(size_t)grow * ldy + col] = f2bf(val);
                }
    }
}

// ---------------------------------------------------------------------------
// Fused scores + mask + softmax + PV, key-split for full occupancy.
// One wg = 32 q-rows x 2048 keys for one (b,h); 4 waves = 2 row-groups x
// 2 key-halves. Each wave: 16 rows x 1024 keys, independent except:
//   - softmax denominators combined across the key-half pair (LDS + barrier)
//   - PV partial accumulators summed across the pair at the end.
// Grid = 2048 wgs -> 8 wgs/CU -> 32 waves/CU (100% occupancy; LDS 17.7KB x 8).
// Pass 1: partial row sums of exp(s) (no max subtract: |s| <= ~8, masked -> 0).
// Pass 2, per 64-key chunk: QK -> regs; weights stored DIRECTLY from regs
// (nontemporal, coalesced 64B per quad); fp32 P dropped into the wave's
// private LDS tile, re-read as PV A-fragments (same-wave LDS => no barrier).
// Block remap: each XCD gets 4 consecutive bh slices (K+V+Q ~3MB < 4MB L2).
// Epilogue: context written directly as hi/lo bf16 planes (even waves only).
// ---------------------------------------------------------------------------
__global__ __launch_bounds__(256) void scores_pv_fused(
    const unsigned short* __restrict__ qH, const unsigned short* __restrict__ kH,
    const unsigned short* __restrict__ vT, const float* __restrict__ maskf,
    float* __restrict__ wout,
    unsigned short* __restrict__ ctxH, unsigned short* __restrict__ ctxL)
{
    __shared__ float ot[4][16][68];     // per-wave private P scratch
    __shared__ float rsx[4][4][4];      // per-wave partial denominators
    int tid = threadIdx.x;
    int w = tid >> 6, lane = tid & 63, lm = lane & 15, quad = lane >> 4;
    int rg = w >> 1, half = w & 1;      // row-group, key-half

    // XCD-aware remap: slot -> (bh, t-chunk); 2048 wgs, 8 XCDs, bijective.
    int slot = blockIdx.x;
    int xcd = slot & 7, rr = slot >> 3;
    int bh = xcd * 4 + (rr >> 6);
    int t0 = (rr & 63) * 32;
    int bsel = bh >> 4, h = bh & 15;
    int k0 = half * (TGT / 2);          // this wave's key range [k0, k0+1024)

    const unsigned short* qrow =
        qH + ((size_t)((t0 + rg * 16 + lm) * BSZN + bsel)) * ED + h * HD + quad * 8;
    short8 a0 = *(const short8*)qrow;
    short8 a1 = *(const short8*)(qrow + 32);

    const float* mrow = maskf + bsel * TGT;
    float* wbh = wout + (size_t)bh * TGT * TGT;
    const unsigned short* vb = vT + (size_t)bh * HD * TGT;

    // ---- pass 1: partial row sums (x2 unroll, independent accumulators) ----
    float rs[4] = {0.f, 0.f, 0.f, 0.f};
    for (int s0 = k0; s0 < k0 + TGT / 2; s0 += 32) {
        int keyA = s0 + lm, keyB = s0 + 16 + lm;
        const unsigned short* krA = kH + ((size_t)(keyA * BSZN + bsel)) * ED + h * HD + quad * 8;
        const unsigned short* krB = kH + ((size_t)(keyB * BSZN + bsel)) * ED + h * HD + quad * 8;
        short8 b0A = *(const short8*)krA;
        short8 b1A = *(const short8*)(krA + 32);
        short8 b0B = *(const short8*)krB;
        short8 b1B = *(const short8*)(krB + 32);
        float mkA = mrow[keyA], mkB = mrow[keyB];
        floatx4 sA = (floatx4){0.f, 0.f, 0.f, 0.f};
        floatx4 sB = (floatx4){0.f, 0.f, 0.f, 0.f};
        sA = __builtin_amdgcn_mfma_f32_16x16x32_bf16(a0, b0A, sA, 0, 0, 0);
        sB = __builtin_amdgcn_mfma_f32_16x16x32_bf16(a0, b0B, sB, 0, 0, 0);
        sA = __builtin_amdgcn_mfma_f32_16x16x32_bf16(a1, b1A, sA, 0, 0, 0);
        sB = __builtin_amdgcn_mfma_f32_16x16x32_bf16(a1, b1B, sB, 0, 0, 0);
#pragma unroll
        for (int r = 0; r < 4; ++r) {
            rs[r] += (mkA != 0.f) ? 0.f : __expf(sA[r]);
            rs[r] += (mkB != 0.f) ? 0.f : __expf(sB[r]);
        }
    }
#pragma unroll
    for (int off = 1; off < 16; off <<= 1) {
#pragma unroll
        for (int r = 0; r < 4; ++r) rs[r] += __shfl_xor(rs[r], off, 64);
    }
    // combine the two key-half partials (fp add is commutative -> deterministic)
    if (lm == 0) {
#pragma unroll
        for (int r = 0; r < 4; ++r) rsx[w][quad][r] = rs[r];
    }
    __syncthreads();
    float rinv[4];
#pragma unroll
    for (int r = 0; r < 4; ++r) rinv[r] = 1.0f / (rs[r] + rsx[w ^ 1][quad][r]);

    // ---- pass 2: weights from regs (nt) + PV from private LDS, no barriers ----
    floatx4 acc[4];
#pragma unroll
    for (int j = 0; j < 4; ++j) acc[j] = (floatx4){0.f, 0.f, 0.f, 0.f};

    float* wrow = wbh + (size_t)(t0 + rg * 16 + quad * 4) * TGT;  // rows quad*4+r

    for (int c0 = k0; c0 < k0 + TGT / 2; c0 += 64) {
#pragma unroll
        for (int sub = 0; sub < 4; ++sub) {
            int key = c0 + sub * 16 + lm;
            const unsigned short* kr = kH + ((size_t)(key * BSZN + bsel)) * ED + h * HD + quad * 8;
            short8 b0 = *(const short8*)kr;
            short8 b1 = *(const short8*)(kr + 32);
            floatx4 s = (floatx4){0.f, 0.f, 0.f, 0.f};
            s = __builtin_amdgcn_mfma_f32_16x16x32_bf16(a0, b0, s, 0, 0, 0);
            s = __builtin_amdgcn_mfma_f32_16x16x32_bf16(a1, b1, s, 0, 0, 0);
            float mk = mrow[key];
#pragma unroll
            for (int r = 0; r < 4; ++r) {
                float e = (mk != 0.f) ? 0.f : __expf(s[r]);
                float v = e * rinv[r];
                __builtin_nontemporal_store(v, &wrow[(size_t)r * TGT + key]);
                ot[w][quad * 4 + r][sub * 16 + lm] = v;   // 2-way bank alias: free
            }
        }
        // PV: A-frag from this wave's own 16 rows (same-wave LDS, no barrier)
#pragma unroll
        for (int kk = 0; kk < 64; kk += 32) {
            const float* pr = &ot[w][lm][kk + quad * 8];
            float4 p0 = *(const float4*)pr;
            float4 p1 = *(const float4*)(pr + 4);
            short8 af;
            af[0] = (short)f2bf(p0.x); af[1] = (short)f2bf(p0.y);
            af[2] = (short)f2bf(p0.z); af[3] = (short)f2bf(p0.w);
            af[4] = (short)f2bf(p1.x); af[5] = (short)f2bf(p1.y);
            af[6] = (short)f2bf(p1.z); af[7] = (short)f2bf(p1.w);
#pragma unroll
            for (int j = 0; j < 4; ++j) {
                short8 bf = *(const short8*)&vb[(size_t)(j * 16 + lm) * TGT + c0 + kk + quad * 8];
                acc[j] = __builtin_amdgcn_mfma_f32_16x16x32_bf16(af, bf, acc[j], 0, 0, 0);
            }
        }
    }

    // ---- combine PV partials across the key-half pair ----
    if (half) {
#pragma unroll
        for (int j = 0; j < 4; ++j)
#pragma unroll
            for (int r = 0; r < 4; ++r)
                ot[w][quad * 4 + r][j * 16 + lm] = acc[j][r];
    }
    __syncthreads();
    if (!half) {
#pragma unroll
        for (int j = 0; j < 4; ++j)
#pragma unroll
            for (int r = 0; r < 4; ++r)
                acc[j][r] += ot[w + 1][quad * 4 + r][j * 16 + lm];

        // ---- epilogue: context -> hi/lo bf16 planes directly ----
#pragma unroll
        for (int j = 0; j < 4; ++j)
#pragma unroll
            for (int r = 0; r < 4; ++r) {
                int t = t0 + rg * 16 + quad * 4 + r;
                int d = j * 16 + lm;
                size_t idx = (size_t)(t * BSZN + bsel) * ED + h * HD + d;
                float val = acc[j][r];
                unsigned short hi = f2bf(val);
                ctxH[idx] = hi;
                ctxL[idx] = f2bf(val - bf2f(hi));
            }
    }
}

// ---------------------------------------------------------------------------
extern "C" void kernel_launch(void* const* d_in, const int* in_sizes, int n_in,
                              void* d_out, int out_size, void* d_ws, size_t ws_size,
                              hipStream_t stream) {
    const float* query = (const float*)d_in[0];
    const unsigned char* mraw = (const unsigned char*)d_in[1];
    const float* qw = (const float*)d_in[2];
    const float* qb = (const float*)d_in[3];
    const float* kw = (const float*)d_in[4];
    const float* kb = (const float*)d_in[5];
    const float* vw = (const float*)d_in[6];
    const float* vb = (const float*)d_in[7];
    const float* ow = (const float*)d_in[8];
    const float* ob = (const float*)d_in[9];

    float* out  = (float*)d_out;                     // attn: ROWS*ED fp32
    float* wout = out + (size_t)ROWS * ED;           // weights: 32*2048*2048 fp32

    // ws layout (bytes), total 44.06 MB (< proven 48 MB budget):
    char* wsb = (char*)d_ws;
    float* maskf           = (float*)(wsb);                       // 16 KB
    unsigned short* qryH   = (unsigned short*)(wsb + 65536);      // 8 MB
    unsigned short* qryL   = qryH + (size_t)ROWS * ED;            // 8 MB
    unsigned short* wWH    = qryL + (size_t)ROWS * ED;            // 2 MB (rotating)
    unsigned short* wWL    = wWH + (size_t)ED * ED;               // 2 MB (rotating)
    unsigned short* qHp    = wWL + (size_t)ED * ED;               // 8 MB
    unsigned short* kHp    = qHp + (size_t)ROWS * ED;             // 8 MB
    unsigned short* vT     = kHp + (size_t)ROWS * ED;             // 8 MB
    // ctx hi/lo planes alias qryH/qryL (dead after the 3 projection GEMMs).
    // NOTE: must NOT alias qHp/kHp — scores_pv_fused reads those while writing ctx.
    unsigned short* ctxH   = qryH;
    unsigned short* ctxL   = qryL;

    dim3 blk(256);
    dim3 ggrid(ED / 64, ROWS / 128);   // (16, 32)

    prep_mask<<<1, blk, 0, stream>>>(mraw, maskf);
    convert_hilo<<<(ROWS * ED / 4 + 255) / 256, blk, 0, stream>>>(query, qryH, qryL, ROWS * ED / 4);

    // Q projection -> bf16 plane, scale 0.125 (bias before scale)
    convert_hilo<<<(ED * ED / 4 + 255) / 256, blk, 0, stream>>>(qw, wWH, wWL, ED * ED / 4);
    gemm_split<<<ggrid, blk, 0, stream>>>(qryH, qryL, wWH, wWL, qb, 0.125f, ED, 1, nullptr, qHp, ED);
    // K projection -> bf16 plane
    convert_hilo<<<(ED * ED / 4 + 255) / 256, blk, 0, stream>>>(kw, wWH, wWL, ED * ED / 4);
    gemm_split<<<ggrid, blk, 0, stream>>>(qryH, qryL, wWH, wWL, kb, 1.0f, ED, 1, nullptr, kHp, ED);
    // V projection -> vT bf16 [bh][d][t]
    convert_hilo<<<(ED * ED / 4 + 255) / 256, blk, 0, stream>>>(vw, wWH, wWL, ED * ED / 4);
    gemm_split<<<ggrid, blk, 0, stream>>>(qryH, qryL, wWH, wWL, vb, 1.0f, ED, 2, nullptr, vT, ED);

    // fused scores + mask + softmax + PV (2048 wgs: 32 bh x 64 row-chunks):
    //   weights -> wout (written exactly once), context -> ctxH/ctxL bf16 planes
    scores_pv_fused<<<dim3(BHN * (TGT / 32)), blk, 0, stream>>>(qHp, kHp, vT, maskf, wout, ctxH, ctxL);

    // out projection: ctx planes -> fp32 out
    convert_hilo<<<(ED * ED / 4 + 255) / 256, blk, 0, stream>>>(ow, wWH, wWL, ED * ED / 4);
    gemm_split<<<ggrid, blk, 0, stream>>>(ctxH, ctxL, wWH, wWL, ob, 1.0f, ED, 0, out, nullptr, ED);
}